// Round 1
// baseline (695.032 us; speedup 1.0000x reference)
//
#include <hip/hip_runtime.h>
#include <hip/hip_bf16.h>

// Attention with softmax over the QUERY axis (axis=1):
//   attn[:,q,k] = exp(S[q,k]) / Z[k],  Z[k] = sum_q exp(S[q,k])
//   out = expS @ diag(1/Z) @ V
// B=2, N=8192, D=256. All matmuls via mfma_f32_16x16x32_bf16.

#define N_ 8192
#define SCALE 0.0625f

typedef __attribute__((ext_vector_type(8))) short short8;
typedef __attribute__((ext_vector_type(4))) float f32x4;
typedef __attribute__((ext_vector_type(4))) unsigned short ushort4_t;

__device__ inline unsigned short f2bf(float f) {
    unsigned int x = __float_as_uint(f);
    unsigned int r = (x + 0x7fffu + ((x >> 16) & 1u)) >> 16;  // RNE
    return (unsigned short)r;
}

__device__ inline short8 ldg8(const unsigned short* p) {
    return *reinterpret_cast<const short8*>(p);
}

__device__ inline short8 cvt8(const float* p) {
    float4 a = *(const float4*)p;
    float4 b = *(const float4*)(p + 4);
    short8 r;
    r[0] = (short)f2bf(a.x); r[1] = (short)f2bf(a.y);
    r[2] = (short)f2bf(a.z); r[3] = (short)f2bf(a.w);
    r[4] = (short)f2bf(b.x); r[5] = (short)f2bf(b.y);
    r[6] = (short)f2bf(b.z); r[7] = (short)f2bf(b.w);
    return r;
}

__device__ inline f32x4 mfma16(short8 a, short8 b, f32x4 c) {
    return __builtin_amdgcn_mfma_f32_16x16x32_bf16(a, b, c, 0, 0, 0);
}

// ---------------------------------------------------------------------------
// Kernel 1: QKV projection. C[n,e] = sum_d x[n,d]*W[e,d]  (x @ W^T)
// Block: 256 thr (4 waves, 2x2), tile 64 rows x 64 cols. Grid: (256, 12).
// cols 0..767 span [Wq | Wk | Wv]. Q,K stored [16384][256] bf16; V stored
// transposed per batch: Vt[b][e][n] bf16.
// ---------------------------------------------------------------------------
__global__ __launch_bounds__(256) void k_proj(
    const float* __restrict__ x, const float* __restrict__ Wq,
    const float* __restrict__ Wk, const float* __restrict__ Wv,
    unsigned short* __restrict__ Qb, unsigned short* __restrict__ Kb,
    unsigned short* __restrict__ Vt)
{
    int rb = blockIdx.x, cb = blockIdx.y;
    int mat = cb >> 2;                 // 0:Q 1:K 2:V
    int e0 = (cb & 3) * 64;
    const float* W = (mat == 0) ? Wq : (mat == 1) ? Wk : Wv;
    int tid = threadIdx.x, w = tid >> 6, lane = tid & 63;
    int lr = lane & 15, lg = lane >> 4;
    int wq = (w >> 1) * 32, wc = (w & 1) * 32;
    int r0 = rb * 64 + wq;

    f32x4 acc[2][2] = {};
    for (int ks = 0; ks < 8; ++ks) {
        int d0 = ks * 32 + lg * 8;
        short8 a0 = cvt8(x + (size_t)(r0 + lr) * 256 + d0);
        short8 a1 = cvt8(x + (size_t)(r0 + 16 + lr) * 256 + d0);
        short8 b0 = cvt8(W + (size_t)(e0 + wc + lr) * 256 + d0);
        short8 b1 = cvt8(W + (size_t)(e0 + wc + 16 + lr) * 256 + d0);
        acc[0][0] = mfma16(a0, b0, acc[0][0]);
        acc[0][1] = mfma16(a0, b1, acc[0][1]);
        acc[1][0] = mfma16(a1, b0, acc[1][0]);
        acc[1][1] = mfma16(a1, b1, acc[1][1]);
    }
    for (int m = 0; m < 2; ++m)
        for (int n = 0; n < 2; ++n) {
            int e = e0 + wc + n * 16 + lr;       // C col = lane&15
            int rbase = r0 + m * 16 + lg * 4;    // C row = (lane>>4)*4+reg
            if (mat < 2) {
                unsigned short* dst = (mat == 0) ? Qb : Kb;
                for (int r = 0; r < 4; ++r)
                    dst[(size_t)(rbase + r) * 256 + e] = f2bf(acc[m][n][r]);
            } else {
                int bidx = rbase >> 13, nr = rbase & 8191;
                ushort4_t v;
                for (int r = 0; r < 4; ++r) v[r] = f2bf(acc[m][n][r]);
                *reinterpret_cast<ushort4_t*>(
                    Vt + ((size_t)bidx * 256 + e) * 8192 + nr) = v;
            }
        }
}

// ---------------------------------------------------------------------------
// Kernel 2: Z[b][k] = sum_q exp(S[q,k]*SCALE). Grid (2 qchunks, 128 ktiles, 2 B),
// block 512 (8 waves). K-tile [64][256] bf16 staged in LDS, XOR-swizzled.
// Each wave: 16 q-rows x 64 k per iter; 32 iters of 128 q.
// ---------------------------------------------------------------------------
__global__ __launch_bounds__(512) void k_zsum(
    const unsigned short* __restrict__ Qb, const unsigned short* __restrict__ Kb,
    float* __restrict__ Zpart)
{
    __shared__ unsigned short sK[64 * 256];  // 32 KB
    __shared__ float zred[8][64];
    int qc = blockIdx.x, kt = blockIdx.y, b = blockIdx.z;
    int tid = threadIdx.x;

    // stage K tile (swizzle: byte ^= (row&7)<<4)
    for (int i = 0; i < 4; ++i) {
        int g = tid + i * 512;            // 2048 granules of 16B
        int r = g >> 5, c = g & 31;
        int off = (r * 512 + c * 16) ^ ((r & 7) << 4);
        *reinterpret_cast<short8*>(reinterpret_cast<char*>(sK) + off) =
            ldg8(Kb + (size_t)(b * N_ + kt * 64 + r) * 256 + c * 8);
    }
    __syncthreads();

    int w = tid >> 6, lane = tid & 63, lr = lane & 15, lg = lane >> 4;
    float zsum[4] = {0.f, 0.f, 0.f, 0.f};
    for (int it = 0; it < 32; ++it) {
        int qb = qc * 4096 + it * 128 + w * 16;
        const unsigned short* qrow = Qb + (size_t)(b * N_ + qb + lr) * 256;
        f32x4 acc[4] = {};
        for (int ks = 0; ks < 8; ++ks) {
            int d0 = ks * 32 + lg * 8;
            short8 a = ldg8(qrow + d0);
#pragma unroll
            for (int n = 0; n < 4; ++n) {
                int krow = n * 16 + lr;
                int off = (krow * 512 + d0 * 2) ^ ((krow & 7) << 4);
                short8 kb = *reinterpret_cast<const short8*>(
                    reinterpret_cast<const char*>(sK) + off);
                acc[n] = mfma16(a, kb, acc[n]);
            }
        }
#pragma unroll
        for (int n = 0; n < 4; ++n)
#pragma unroll
            for (int r = 0; r < 4; ++r)
                zsum[n] += __expf(acc[n][r] * SCALE);
    }
#pragma unroll
    for (int n = 0; n < 4; ++n) {
        float v = zsum[n];
        v += __shfl_xor(v, 16);
        v += __shfl_xor(v, 32);
        if (lg == 0) zred[w][n * 16 + lr] = v;
    }
    __syncthreads();
    if (tid < 64) {
        float s = 0.f;
        for (int ww = 0; ww < 8; ++ww) s += zred[ww][tid];
        Zpart[(size_t)(qc * 2 + b) * N_ + kt * 64 + tid] = s;
    }
}

__global__ void k_rz(const float* __restrict__ Zpart, float* __restrict__ rZ) {
    int t = blockIdx.x * 256 + threadIdx.x;  // 16384
    int b = t >> 13, k = t & 8191;
    float z = Zpart[(size_t)b * N_ + k] + Zpart[(size_t)(2 + b) * N_ + k];
    rZ[t] = 1.0f / z;
}

// ---------------------------------------------------------------------------
// Kernel 3: out[q,d] = sum_k exp(S[q,k]*SCALE)*rZ[k]*V[k,d].
// Grid (128 qtiles, 2 B), block 512 (8 waves). Per iter (k-tile 64):
// stage K [64][256] + Vt [256][64] in LDS (swizzled); each wave computes a
// 16q x 32k S strip -> P (bf16, swizzled LDS) -> PV into 16q x 128d acc.
// ---------------------------------------------------------------------------
__global__ __launch_bounds__(512) void k_attn(
    const unsigned short* __restrict__ Qb, const unsigned short* __restrict__ Kb,
    const unsigned short* __restrict__ Vt, const float* __restrict__ rZ,
    float* __restrict__ out)
{
    extern __shared__ char smem[];
    // [0,32768): K tile [64][256] bf16; [32768,65536): Vt tile [256][64];
    // [65536,73728): P [64][64] bf16
    int qt = blockIdx.x, b = blockIdx.y;
    int tid = threadIdx.x, w = tid >> 6, lane = tid & 63;
    int lr = lane & 15, lg = lane >> 4;
    int wq = (w & 3) * 16, half = w >> 2;
    int qbase = qt * 64;

    // hoist this wave's Q fragments (16 rows x 256 d = 8 frags)
    const unsigned short* qrow = Qb + (size_t)(b * N_ + qbase + wq + lr) * 256;
    short8 qfr[8];
#pragma unroll
    for (int ks = 0; ks < 8; ++ks) qfr[ks] = ldg8(qrow + ks * 32 + lg * 8);

    f32x4 acco[8] = {};
    for (int kt = 0; kt < 128; ++kt) {
        // stage K and Vt tiles
#pragma unroll
        for (int i = 0; i < 4; ++i) {
            int g = tid + i * 512;
            int r = g >> 5, c = g & 31;
            int offk = (r * 512 + c * 16) ^ ((r & 7) << 4);
            *reinterpret_cast<short8*>(smem + offk) =
                ldg8(Kb + (size_t)(b * N_ + kt * 64 + r) * 256 + c * 8);
            int d = g >> 3, c2 = g & 7;
            int offv = (d * 128 + c2 * 16) ^ ((d & 7) << 4);
            *reinterpret_cast<short8*>(smem + 32768 + offv) =
                ldg8(Vt + ((size_t)b * 256 + d) * 8192 + kt * 64 + c2 * 8);
        }
        __syncthreads();

        // S strip: 16q x 32k
        f32x4 acc[2] = {};
#pragma unroll
        for (int ks = 0; ks < 8; ++ks) {
            int d0 = ks * 32 + lg * 8;
#pragma unroll
            for (int n = 0; n < 2; ++n) {
                int krow = half * 32 + n * 16 + lr;
                int off = (krow * 512 + d0 * 2) ^ ((krow & 7) << 4);
                short8 kb = *reinterpret_cast<const short8*>(smem + off);
                acc[n] = mfma16(qfr[ks], kb, acc[n]);
            }
        }
        // P = exp(S)*rZ -> LDS (bf16, swizzled)
#pragma unroll
        for (int n = 0; n < 2; ++n) {
            int kcol = half * 32 + n * 16 + lr;
            float rz = rZ[(size_t)b * N_ + kt * 64 + kcol];
#pragma unroll
            for (int r = 0; r < 4; ++r) {
                float p = __expf(acc[n][r] * SCALE) * rz;
                int q = wq + lg * 4 + r;
                int off = (q * 128 + kcol * 2) ^ ((q & 7) << 4);
                *reinterpret_cast<unsigned short*>(smem + 65536 + off) = f2bf(p);
            }
        }
        __syncthreads();

        // PV: 16q x 128d (this wave's half)
#pragma unroll
        for (int ks2 = 0; ks2 < 2; ++ks2) {
            int kk = ks2 * 32 + lg * 8;
            int qq = wq + lr;
            int offa = (qq * 128 + kk * 2) ^ ((qq & 7) << 4);
            short8 pa = *reinterpret_cast<const short8*>(smem + 65536 + offa);
#pragma unroll
            for (int n = 0; n < 8; ++n) {
                int d = half * 128 + n * 16 + lr;
                int offb = (d * 128 + kk * 2) ^ ((d & 7) << 4);
                short8 vb = *reinterpret_cast<const short8*>(smem + 32768 + offb);
                acco[n] = mfma16(pa, vb, acco[n]);
            }
        }
        __syncthreads();
    }
    // store f32 output
#pragma unroll
    for (int n = 0; n < 8; ++n) {
        int d = half * 128 + n * 16 + lr;
        int q0 = qbase + wq + lg * 4;
#pragma unroll
        for (int r = 0; r < 4; ++r)
            out[(size_t)(b * N_ + q0 + r) * 256 + d] = acco[n][r];
    }
}

extern "C" void kernel_launch(void* const* d_in, const int* in_sizes, int n_in,
                              void* d_out, int out_size, void* d_ws, size_t ws_size,
                              hipStream_t stream)
{
    const float* x  = (const float*)d_in[0];
    const float* Wq = (const float*)d_in[1];
    const float* Wk = (const float*)d_in[2];
    const float* Wv = (const float*)d_in[3];

    char* ws = (char*)d_ws;
    unsigned short* Qb = (unsigned short*)(ws);              //  8 MB
    unsigned short* Kb = (unsigned short*)(ws + 8388608);    //  8 MB
    unsigned short* Vt = (unsigned short*)(ws + 16777216);   //  8 MB
    float* Zpart       = (float*)(ws + 25165824);            // 256 KB
    float* rZ          = (float*)(ws + 25427968);            //  64 KB
    float* out = (float*)d_out;

    k_proj<<<dim3(256, 12), dim3(256), 0, stream>>>(x, Wq, Wk, Wv, Qb, Kb, Vt);
    k_zsum<<<dim3(2, 128, 2), dim3(512), 0, stream>>>(Qb, Kb, Zpart);
    k_rz<<<dim3(64), dim3(256), 0, stream>>>(Zpart, rZ);
    hipFuncSetAttribute((const void*)k_attn,
                        hipFuncAttributeMaxDynamicSharedMemorySize, 73728);
    k_attn<<<dim3(128, 2), dim3(512), 73728, stream>>>(Qb, Kb, Vt, rZ, out);
}

// Round 2
// 444.663 us; speedup vs baseline: 1.5631x; 1.5631x over previous
//
#include <hip/hip_runtime.h>
#include <hip/hip_bf16.h>

// Attention with softmax over the QUERY axis (axis=1):
//   attn[:,q,k] = exp(S[q,k]) / Z[k],  Z[k] = sum_q exp(S[q,k])
//   out = expS @ (diag(1/Z) V)   -- rZ folded into V by k_scalev.
// B=2, N=8192, D=256. All matmuls via mfma_f32_16x16x32_bf16.

#define N_ 8192
#define SCALE 0.0625f

typedef __attribute__((ext_vector_type(8))) short short8;
typedef __attribute__((ext_vector_type(4))) float f32x4;
typedef __attribute__((ext_vector_type(4))) unsigned short ushort4_t;

__device__ inline unsigned short f2bf(float f) {
    unsigned int x = __float_as_uint(f);
    unsigned int r = (x + 0x7fffu + ((x >> 16) & 1u)) >> 16;  // RNE
    return (unsigned short)r;
}

__device__ inline short8 ldg8(const unsigned short* p) {
    return *reinterpret_cast<const short8*>(p);
}

__device__ inline short8 cvt8(const float* p) {
    float4 a = *(const float4*)p;
    float4 b = *(const float4*)(p + 4);
    short8 r;
    r[0] = (short)f2bf(a.x); r[1] = (short)f2bf(a.y);
    r[2] = (short)f2bf(a.z); r[3] = (short)f2bf(a.w);
    r[4] = (short)f2bf(b.x); r[5] = (short)f2bf(b.y);
    r[6] = (short)f2bf(b.z); r[7] = (short)f2bf(b.w);
    return r;
}

__device__ inline f32x4 mfma16(short8 a, short8 b, f32x4 c) {
    return __builtin_amdgcn_mfma_f32_16x16x32_bf16(a, b, c, 0, 0, 0);
}

typedef __attribute__((address_space(3))) unsigned int lds_u32;
typedef __attribute__((address_space(1))) const unsigned int glb_u32;
__device__ __forceinline__ void gll16(const void* g, void* l) {
    __builtin_amdgcn_global_load_lds((glb_u32*)g, (lds_u32*)l, 16, 0, 0);
}
#define WAIT_VM0()   asm volatile("s_waitcnt vmcnt(0)" ::: "memory")
#define WAIT_LGKM0() asm volatile("s_waitcnt lgkmcnt(0)" ::: "memory")
#define BARRIER()    __builtin_amdgcn_s_barrier()

// ---------------------------------------------------------------------------
// Kernel 1: QKV projection (unchanged from R1).
// ---------------------------------------------------------------------------
__global__ __launch_bounds__(256) void k_proj(
    const float* __restrict__ x, const float* __restrict__ Wq,
    const float* __restrict__ Wk, const float* __restrict__ Wv,
    unsigned short* __restrict__ Qb, unsigned short* __restrict__ Kb,
    unsigned short* __restrict__ Vt)
{
    int rb = blockIdx.x, cb = blockIdx.y;
    int mat = cb >> 2;                 // 0:Q 1:K 2:V
    int e0 = (cb & 3) * 64;
    const float* W = (mat == 0) ? Wq : (mat == 1) ? Wk : Wv;
    int tid = threadIdx.x, w = tid >> 6, lane = tid & 63;
    int lr = lane & 15, lg = lane >> 4;
    int wq = (w >> 1) * 32, wc = (w & 1) * 32;
    int r0 = rb * 64 + wq;

    f32x4 acc[2][2] = {};
    for (int ks = 0; ks < 8; ++ks) {
        int d0 = ks * 32 + lg * 8;
        short8 a0 = cvt8(x + (size_t)(r0 + lr) * 256 + d0);
        short8 a1 = cvt8(x + (size_t)(r0 + 16 + lr) * 256 + d0);
        short8 b0 = cvt8(W + (size_t)(e0 + wc + lr) * 256 + d0);
        short8 b1 = cvt8(W + (size_t)(e0 + wc + 16 + lr) * 256 + d0);
        acc[0][0] = mfma16(a0, b0, acc[0][0]);
        acc[0][1] = mfma16(a0, b1, acc[0][1]);
        acc[1][0] = mfma16(a1, b0, acc[1][0]);
        acc[1][1] = mfma16(a1, b1, acc[1][1]);
    }
    for (int m = 0; m < 2; ++m)
        for (int n = 0; n < 2; ++n) {
            int e = e0 + wc + n * 16 + lr;
            int rbase = r0 + m * 16 + lg * 4;
            if (mat < 2) {
                unsigned short* dst = (mat == 0) ? Qb : Kb;
                for (int r = 0; r < 4; ++r)
                    dst[(size_t)(rbase + r) * 256 + e] = f2bf(acc[m][n][r]);
            } else {
                int bidx = rbase >> 13, nr = rbase & 8191;
                ushort4_t v;
                for (int r = 0; r < 4; ++r) v[r] = f2bf(acc[m][n][r]);
                *reinterpret_cast<ushort4_t*>(
                    Vt + ((size_t)bidx * 256 + e) * 8192 + nr) = v;
            }
        }
}

// ---------------------------------------------------------------------------
// Kernel 2: Z[b][k] = sum_q exp(S[q,k]*SCALE) (unchanged from R1).
// ---------------------------------------------------------------------------
__global__ __launch_bounds__(512) void k_zsum(
    const unsigned short* __restrict__ Qb, const unsigned short* __restrict__ Kb,
    float* __restrict__ Zpart)
{
    __shared__ unsigned short sK[64 * 256];
    __shared__ float zred[8][64];
    int qc = blockIdx.x, kt = blockIdx.y, b = blockIdx.z;
    int tid = threadIdx.x;

    for (int i = 0; i < 4; ++i) {
        int g = tid + i * 512;
        int r = g >> 5, c = g & 31;
        int off = (r * 512 + c * 16) ^ ((r & 7) << 4);
        *reinterpret_cast<short8*>(reinterpret_cast<char*>(sK) + off) =
            ldg8(Kb + (size_t)(b * N_ + kt * 64 + r) * 256 + c * 8);
    }
    __syncthreads();

    int w = tid >> 6, lane = tid & 63, lr = lane & 15, lg = lane >> 4;
    float zsum[4] = {0.f, 0.f, 0.f, 0.f};
    for (int it = 0; it < 32; ++it) {
        int qb = qc * 4096 + it * 128 + w * 16;
        const unsigned short* qrow = Qb + (size_t)(b * N_ + qb + lr) * 256;
        f32x4 acc[4] = {};
        for (int ks = 0; ks < 8; ++ks) {
            int d0 = ks * 32 + lg * 8;
            short8 a = ldg8(qrow + d0);
#pragma unroll
            for (int n = 0; n < 4; ++n) {
                int krow = n * 16 + lr;
                int off = (krow * 512 + d0 * 2) ^ ((krow & 7) << 4);
                short8 kb = *reinterpret_cast<const short8*>(
                    reinterpret_cast<const char*>(sK) + off);
                acc[n] = mfma16(a, kb, acc[n]);
            }
        }
#pragma unroll
        for (int n = 0; n < 4; ++n)
#pragma unroll
            for (int r = 0; r < 4; ++r)
                zsum[n] += __expf(acc[n][r] * SCALE);
    }
#pragma unroll
    for (int n = 0; n < 4; ++n) {
        float v = zsum[n];
        v += __shfl_xor(v, 16);
        v += __shfl_xor(v, 32);
        if (lg == 0) zred[w][n * 16 + lr] = v;
    }
    __syncthreads();
    if (tid < 64) {
        float s = 0.f;
        for (int ww = 0; ww < 8; ++ww) s += zred[ww][tid];
        Zpart[(size_t)(qc * 2 + b) * N_ + kt * 64 + tid] = s;
    }
}

__global__ void k_rz(const float* __restrict__ Zpart, float* __restrict__ rZ) {
    int t = blockIdx.x * 256 + threadIdx.x;  // 16384
    int b = t >> 13, k = t & 8191;
    float z = Zpart[(size_t)b * N_ + k] + Zpart[(size_t)(2 + b) * N_ + k];
    rZ[t] = 1.0f / z;
}

// ---------------------------------------------------------------------------
// Kernel 2.5: V' = V * rZ (in place on Vt, bf16). Removes rZ from hot loop.
// ---------------------------------------------------------------------------
__global__ __launch_bounds__(256) void k_scalev(
    unsigned short* __restrict__ Vt, const float* __restrict__ rZ)
{
    int t = blockIdx.x * 256 + threadIdx.x;   // 0..524287 granules of 8
    int b = t >> 18, g = t & 262143;
    int d = g >> 10, k8 = (g & 1023) * 8;
    unsigned short* p = Vt + ((size_t)b * 256 + d) * 8192 + k8;
    short8 v = *reinterpret_cast<short8*>(p);
    const float* rz = rZ + b * 8192 + k8;
    float4 r0 = *(const float4*)rz, r1 = *(const float4*)(rz + 4);
    float rv[8] = {r0.x, r0.y, r0.z, r0.w, r1.x, r1.y, r1.z, r1.w};
    short8 o;
#pragma unroll
    for (int j = 0; j < 8; ++j) {
        float f = __uint_as_float(((unsigned)(unsigned short)v[j]) << 16) * rv[j];
        o[j] = (short)f2bf(f);
    }
    *reinterpret_cast<short8*>(p) = o;
}

// ---------------------------------------------------------------------------
// Kernel 3: out[q,d] = sum_k exp(S[q,k]*SCALE) * V'[k,d].
// Grid (128 qtiles, 2 B), block 512 (8 waves), qtile 64.
// Double-buffered K/V via async global_load_lds (pre-swizzled source),
// 2 raw barriers per kt, Q hoisted to regs, per-wave tiles 32qx16k (S) and
// 32qx64d (PV).  LDS: K 2x32K @0, V 2x32K @65536, P 8K @131072 = 136 KB.
// ---------------------------------------------------------------------------
__global__ __launch_bounds__(512, 1) void k_attn(
    const unsigned short* __restrict__ Qb, const unsigned short* __restrict__ Kb,
    const unsigned short* __restrict__ Vt, float* __restrict__ out)
{
    extern __shared__ char smem[];
    const int qt = blockIdx.x, b = blockIdx.y;
    const int tid = threadIdx.x, w = tid >> 6, lane = tid & 63;
    const int lr = lane & 15, lg = lane >> 4;
    const int qbase = qt * 64;
    const int wqs = w >> 2;          // q strip: rows wqs*32 .. +32
    const int wks = w & 3;           // S k-quarter (16 k)
    const int wds = w & 3;           // PV d-quarter (64 d)
    const int q0 = wqs * 32;

    // staging sources, pre-swizzled so linear LDS dest == swizzled layout.
    // K granule L: r=L>>5, c=(L&31)^(r&7). V granule L: d=L>>3, c2=(L&7)^(d&7).
    const unsigned short* srcK[4];
    const unsigned short* srcV[4];
#pragma unroll
    for (int i = 0; i < 4; ++i) {
        int L = w * 256 + i * 64 + lane;
        int r = L >> 5, c = (L & 31) ^ (r & 7);
        srcK[i] = Kb + (size_t)(b * N_ + r) * 256 + c * 8;
        int d = L >> 3, c2 = (L & 7) ^ (d & 7);
        srcV[i] = Vt + ((size_t)b * 256 + d) * 8192 + c2 * 8;
    }

    // prologue: stage tile 0 into buffer 0 (async)
#pragma unroll
    for (int i = 0; i < 4; ++i) {
        gll16(srcK[i], smem + (size_t)(w * 256 + i * 64) * 16);
        gll16(srcV[i], smem + 65536 + (size_t)(w * 256 + i * 64) * 16);
        srcK[i] += 64 * 256;
        srcV[i] += 64;
    }

    // hoist Q fragments: 32 rows (2 frags) x 8 k-slices
    short8 qfr[2][8];
#pragma unroll
    for (int qf = 0; qf < 2; ++qf) {
        const unsigned short* qrow =
            Qb + (size_t)(b * N_ + qbase + q0 + qf * 16 + lr) * 256;
#pragma unroll
        for (int ks = 0; ks < 8; ++ks)
            qfr[qf][ks] = ldg8(qrow + ks * 32 + lg * 8);
    }

    f32x4 acco[2][4] = {};

    for (int kt = 0; kt < 128; ++kt) {
        const int cur = kt & 1;
        char* sK = smem + cur * 32768;
        char* sV = smem + 65536 + cur * 32768;
        char* sP = smem + 131072;

        WAIT_VM0();                  // this wave's staging of tile kt done
        BARRIER();                   // all waves' slices done
        __builtin_amdgcn_sched_barrier(0);

        // issue next tile's staging into the other buffer (flies over S+PV)
        if (kt + 1 < 128) {
            char* nK = smem + (cur ^ 1) * 32768;
            char* nV = smem + 65536 + (cur ^ 1) * 32768;
#pragma unroll
            for (int i = 0; i < 4; ++i) {
                gll16(srcK[i], nK + (size_t)(w * 256 + i * 64) * 16);
                gll16(srcV[i], nV + (size_t)(w * 256 + i * 64) * 16);
                srcK[i] += 64 * 256;
                srcV[i] += 64;
            }
        }

        // ---- S phase: 32q x 16k, K from LDS, Q from regs ----
        f32x4 sacc[2] = {};
        __builtin_amdgcn_s_setprio(1);
#pragma unroll
        for (int ks = 0; ks < 8; ++ks) {
            int krow = wks * 16 + lr;
            int coff = (ks * 32 + lg * 8) * 2;
            int off = (krow * 512 + coff) ^ ((krow & 7) << 4);
            short8 kb = *reinterpret_cast<const short8*>(sK + off);
            sacc[0] = mfma16(qfr[0][ks], kb, sacc[0]);
            sacc[1] = mfma16(qfr[1][ks], kb, sacc[1]);
        }
        __builtin_amdgcn_s_setprio(0);

        // ---- P = exp(S*SCALE) -> LDS bf16 (V' already carries rZ) ----
#pragma unroll
        for (int qf = 0; qf < 2; ++qf)
#pragma unroll
            for (int r = 0; r < 4; ++r) {
                float p = __expf(sacc[qf][r] * SCALE);
                int q = q0 + qf * 16 + lg * 4 + r;
                int kcol = wks * 16 + lr;
                int off = (q * 128 + kcol * 2) ^ ((q & 7) << 4);
                *reinterpret_cast<unsigned short*>(sP + off) = f2bf(p);
            }

        WAIT_LGKM0();                // P writes visible
        BARRIER();
        __builtin_amdgcn_sched_barrier(0);

        // ---- PV phase: 32q x 64d over 64 k ----
        __builtin_amdgcn_s_setprio(1);
#pragma unroll
        for (int kk = 0; kk < 2; ++kk) {
            int coff = (kk * 32 + lg * 8) * 2;
            short8 pa[2];
#pragma unroll
            for (int qf = 0; qf < 2; ++qf) {
                int qq = q0 + qf * 16 + lr;
                int offa = (qq * 128 + coff) ^ ((qq & 7) << 4);
                pa[qf] = *reinterpret_cast<const short8*>(sP + offa);
            }
#pragma unroll
            for (int df = 0; df < 4; ++df) {
                int d = wds * 64 + df * 16 + lr;
                int offb = (d * 128 + coff) ^ ((d & 7) << 4);
                short8 vb = *reinterpret_cast<const short8*>(sV + offb);
                acco[0][df] = mfma16(pa[0], vb, acco[0][df]);
                acco[1][df] = mfma16(pa[1], vb, acco[1][df]);
            }
        }
        __builtin_amdgcn_s_setprio(0);
    }

    // epilogue: f32 store
#pragma unroll
    for (int qf = 0; qf < 2; ++qf)
#pragma unroll
        for (int df = 0; df < 4; ++df) {
            int d = wds * 64 + df * 16 + lr;
            int q0r = qbase + q0 + qf * 16 + lg * 4;
#pragma unroll
            for (int r = 0; r < 4; ++r)
                out[(size_t)(b * N_ + q0r + r) * 256 + d] = acco[qf][df][r];
        }
}

extern "C" void kernel_launch(void* const* d_in, const int* in_sizes, int n_in,
                              void* d_out, int out_size, void* d_ws, size_t ws_size,
                              hipStream_t stream)
{
    const float* x  = (const float*)d_in[0];
    const float* Wq = (const float*)d_in[1];
    const float* Wk = (const float*)d_in[2];
    const float* Wv = (const float*)d_in[3];

    char* ws = (char*)d_ws;
    unsigned short* Qb = (unsigned short*)(ws);              //  8 MB
    unsigned short* Kb = (unsigned short*)(ws + 8388608);    //  8 MB
    unsigned short* Vt = (unsigned short*)(ws + 16777216);   //  8 MB
    float* Zpart       = (float*)(ws + 25165824);            // 256 KB
    float* rZ          = (float*)(ws + 25427968);            //  64 KB
    float* out = (float*)d_out;

    k_proj<<<dim3(256, 12), dim3(256), 0, stream>>>(x, Wq, Wk, Wv, Qb, Kb, Vt);
    k_zsum<<<dim3(2, 128, 2), dim3(512), 0, stream>>>(Qb, Kb, Zpart);
    k_rz<<<dim3(64), dim3(256), 0, stream>>>(Zpart, rZ);
    k_scalev<<<dim3(2048), dim3(256), 0, stream>>>(Vt, rZ);
    hipFuncSetAttribute((const void*)k_attn,
                        hipFuncAttributeMaxDynamicSharedMemorySize, 139264);
    k_attn<<<dim3(128, 2), dim3(512), 139264, stream>>>(Qb, Kb, Vt, out);
}